// Round 4
// baseline (331.217 us; speedup 1.0000x reference)
//
#include <hip/hip_runtime.h>
#include <math.h>

constexpr int kN  = 4096;
constexpr int kFI = 128;
constexpr int kFO = 64;
constexpr int kH  = 4;
constexpr int kHF = 256;   // kH*kFO
constexpr float kNegInf = -1e9f;
constexpr float kLnEps  = 1e-5f;
constexpr float kL2E    = 1.44269504f;

typedef short bf16x8 __attribute__((ext_vector_type(8)));
typedef float f32x4  __attribute__((ext_vector_type(4)));

__device__ __forceinline__ float wave_sum(float v){
  #pragma unroll
  for (int s = 32; s > 0; s >>= 1) v += __shfl_xor(v, s, 64);
  return v;
}

__device__ __forceinline__ unsigned short f2bf(float x){
  unsigned u = __float_as_uint(x);
  u = (u + 0x7fffu + ((u >> 16) & 1u)) >> 16;
  return (unsigned short)u;
}
__device__ __forceinline__ unsigned f2bf_pk(float a, float b){
  return (unsigned)f2bf(a) | ((unsigned)f2bf(b) << 16);
}

// ---------------------------------------------------------------------------
// K0: transpose skw [256][128] -> skwT [128][256] so k_proj reads coalesce.
// ---------------------------------------------------------------------------
__global__ __launch_bounds__(256) void k_tr(
    const float* __restrict__ skw, float* __restrict__ skwT)
{
  const int k  = blockIdx.x;      // 0..127
  const int hf = threadIdx.x;     // 0..255
  skwT[k*kHF + hf] = skw[hf*kFI + k];
}

// ---------------------------------------------------------------------------
// K1: proj[h][n][o], ga/gb scores, skip = nodes @ skw^T. 8 nodes/block,
// 512 blocks. Plain loop (R2: lambda/pointer prefetch spilled to scratch).
// ---------------------------------------------------------------------------
__global__ __launch_bounds__(256) void k_proj(
    const float* __restrict__ nodes, const float* __restrict__ pp,
    const float* __restrict__ ssrc,  const float* __restrict__ stgt,
    const float* __restrict__ skwT,
    float* __restrict__ proj, float* __restrict__ ga, float* __restrict__ gb,
    float* __restrict__ skipo)
{
  __shared__ float feat[8][kFI];    // 4 KB
  const int tid = threadIdx.x;
  const int n0  = blockIdx.x * 8;
  for (int idx = tid; idx < 8*kFI; idx += 256)
    feat[idx >> 7][idx & 127] = nodes[n0*kFI + idx];
  __syncthreads();
  const int h = tid >> 6, o = tid & 63;
  float accP[8], accS[8];
  #pragma unroll
  for (int n = 0; n < 8; ++n){ accP[n] = 0.f; accS[n] = 0.f; }
  for (int k0 = 0; k0 < kFI; k0 += 4){
    float p[4], w[4];
    #pragma unroll
    for (int u = 0; u < 4; ++u){
      p[u] = pp[(h*kFI + k0+u)*kFO + o];
      w[u] = skwT[(k0+u)*kHF + tid];
    }
    #pragma unroll
    for (int n = 0; n < 8; ++n){
      const float4 f4 = *(const float4*)&feat[n][k0];
      accP[n] = fmaf(f4.x, p[0], fmaf(f4.y, p[1],
                fmaf(f4.z, p[2], fmaf(f4.w, p[3], accP[n]))));
      accS[n] = fmaf(f4.x, w[0], fmaf(f4.y, w[1],
                fmaf(f4.z, w[2], fmaf(f4.w, w[3], accS[n]))));
    }
  }
  const float sa = ssrc[h*kFO + o];
  const float sb = stgt[h*kFO + o];
  #pragma unroll
  for (int n = 0; n < 8; ++n){
    proj[(h*kN + n0+n)*kFO + o] = accP[n];
    skipo[(n0+n)*kHF + tid]     = accS[n];
    const float va = wave_sum(accP[n] * sa);
    const float vb = wave_sum(accP[n] * sb);
    if (o == 0){ ga[h*kN + n0+n] = va; gb[h*kN + n0+n] = vb; }
  }
}

// ---------------------------------------------------------------------------
// K2: column pass + row LN stat partials. R3 post-mortem: three latency-
// schedule variants all landed 75-82us -> stop tuning, cut traffic. The
// 64MB mask write is GONE (k_aggr recomputes m from L3-warm degm/bondm).
// hbm_bytes 173 -> ~110 MB.
// ---------------------------------------------------------------------------
template<int RS>
__global__ __launch_bounds__(256) void k_colsum(
    const float* __restrict__ degm, const float* __restrict__ bondm,
    const float* __restrict__ ga,   const float* __restrict__ gb,
    const int* __restrict__ cutp,
    float* __restrict__ Spart, float* __restrict__ statg)
{
  const int j0 = (blockIdx.x * 256 + threadIdx.x) * 4;
  const int lane = threadIdx.x & 63;
  const float cut = (float)cutp[0];
  float4 bv[kH]; f32x4 sv[kH];
  #pragma unroll
  for (int h = 0; h < kH; ++h){
    bv[h] = *(const float4*)&gb[h*kN + j0];
    sv[h] = (f32x4){0.f, 0.f, 0.f, 0.f};
  }
  float msum[RS], msq[RS];
  #pragma unroll
  for (int r = 0; r < RS; ++r){ msum[r] = 0.f; msq[r] = 0.f; }

  const int i0 = blockIdx.y * RS;
  #pragma unroll
  for (int ib = 0; ib < RS; ib += 8){
    float4 dg[8], bd[8];
    #pragma unroll
    for (int u = 0; u < 8; ++u){
      const size_t off = (size_t)(i0+ib+u)*kN + j0;
      dg[u] = *(const float4*)&degm[off];
      bd[u] = *(const float4*)&bondm[off];
    }
    #pragma unroll
    for (int u = 0; u < 8; ++u){
      const int i = i0 + ib + u;
      float4 m;
      {
        float w0 = dg[u].x + bd[u].x, w1 = dg[u].y + bd[u].y;
        float w2 = dg[u].z + bd[u].z, w3 = dg[u].w + bd[u].w;
        m.x = w0 > 0.f ? w0 : (bd[u].x > cut ? bd[u].x + w0 : kNegInf);
        m.y = w1 > 0.f ? w1 : (bd[u].y > cut ? bd[u].y + w1 : kNegInf);
        m.z = w2 > 0.f ? w2 : (bd[u].z > cut ? bd[u].z + w2 : kNegInf);
        m.w = w3 > 0.f ? w3 : (bd[u].w > cut ? bd[u].w + w3 : kNegInf);
      }
      msum[ib+u] += (m.x + m.y) + (m.z + m.w);
      msq[ib+u]  += fmaf(m.x, m.x, fmaf(m.y, m.y, fmaf(m.z, m.z, m.w*m.w)));
      const float4 ml = {m.x*kL2E, m.y*kL2E, m.z*kL2E, m.w*kL2E};
      #pragma unroll
      for (int h = 0; h < kH; ++h){
        const float a = ga[h*kN + i];
        float t0 = a + bv[h].x, t1 = a + bv[h].y;
        float t2 = a + bv[h].z, t3 = a + bv[h].w;
        t0 = fmaxf(t0, 0.2f*t0); t1 = fmaxf(t1, 0.2f*t1);
        t2 = fmaxf(t2, 0.2f*t2); t3 = fmaxf(t3, 0.2f*t3);
        sv[h][0] += exp2f(fmaf(t0, kL2E, ml.x));
        sv[h][1] += exp2f(fmaf(t1, kL2E, ml.y));
        sv[h][2] += exp2f(fmaf(t2, kL2E, ml.z));
        sv[h][3] += exp2f(fmaf(t3, kL2E, ml.w));
      }
    }
  }
  #pragma unroll
  for (int h = 0; h < kH; ++h)
    *(float4*)&Spart[(size_t)(blockIdx.y*kH + h)*kN + j0] = *(float4*)&sv[h];

  #pragma unroll
  for (int r = 0; r < RS; ++r){
    const float s1 = wave_sum(msum[r]);
    const float s2 = wave_sum(msq[r]);
    if (lane == 0){
      atomicAdd(&statg[2*(i0+r)+0], s1);
      atomicAdd(&statg[2*(i0+r)+1], s2);
    }
  }
}

// ---------------------------------------------------------------------------
// K2b: reduce S partials. grid (256, 8); atomicAdd into pre-zeroed S.
// ---------------------------------------------------------------------------
__global__ __launch_bounds__(256) void k_sred(
    const float* __restrict__ Spart, float* __restrict__ S, int strips)
{
  __shared__ float red[4][64];
  const int hj0  = blockIdx.x * 64;
  const int lane = threadIdx.x & 63;
  const int g    = threadIdx.x >> 6;
  const int per_chunk = strips >> 3;
  const int per_wave  = per_chunk >> 2;
  const int p0 = blockIdx.y*per_chunk + g*per_wave;
  float s0=0.f, s1=0.f, s2=0.f, s3=0.f;
  for (int p = p0; p < p0 + per_wave; p += 4){
    s0 += Spart[(size_t)(p+0)*kH*kN + hj0 + lane];
    s1 += Spart[(size_t)(p+1)*kH*kN + hj0 + lane];
    s2 += Spart[(size_t)(p+2)*kH*kN + hj0 + lane];
    s3 += Spart[(size_t)(p+3)*kH*kN + hj0 + lane];
  }
  red[g][lane] = (s0+s1)+(s2+s3);
  __syncthreads();
  if (threadIdx.x < 64)
    atomicAdd(&S[hj0+lane],
              (red[0][lane]+red[1][lane])+(red[2][lane]+red[3][lane]));
}

// ---------------------------------------------------------------------------
// K2c: finalize LN stats: statg2[i] = (mu, rsqrt(var+eps))
// ---------------------------------------------------------------------------
__global__ __launch_bounds__(256) void k_stat(
    const float* __restrict__ statg, float* __restrict__ statg2)
{
  const int i = blockIdx.x * 256 + threadIdx.x;
  const float mu  = statg[2*i] * (1.f/kN);
  const float var = statg[2*i+1] * (1.f/kN) - mu*mu;
  statg2[2*i+0] = mu;
  statg2[2*i+1] = rsqrtf(var + kLnEps);
}

// ---------------------------------------------------------------------------
// K2d: pack pS = proj/S into bf16 MFMA B-fragment layout.
// pSpack[h][kb][nt][lane][r] = bf16(pS[h][ kb*32+(lane>>4)*8+r ][ nt*16+(lane&15) ])
// ---------------------------------------------------------------------------
__global__ __launch_bounds__(256) void k_pack(
    const float* __restrict__ proj, const float* __restrict__ S,
    unsigned short* __restrict__ pSpack)
{
  const int t = blockIdx.x * 256 + threadIdx.x;   // 131072 total
  const int L  = t & 63;
  const int nt = (t >> 6) & 3;
  const int kb = (t >> 8) & 127;
  const int h  = t >> 15;
  const int f  = nt*16 + (L & 15);
  const int jb = kb*32 + (L >> 4)*8;
  union { unsigned short s[8]; uint4 v; } u;
  #pragma unroll
  for (int r = 0; r < 8; ++r){
    const int j = jb + r;
    u.s[r] = f2bf(proj[(size_t)(h*kN + j)*kFO + f] / S[h*kN + j]);
  }
  ((uint4*)pSpack)[t] = u.v;
}

// ---------------------------------------------------------------------------
// K3: aggregation via MFMA -- BARRIER-FREE rewrite. Each wave owns 16 rows
// and ALL 4 heads: lane L holds A-row = L&15, k-cols = (L>>4)*8+r. Per
// 32-col chunk: recompute m from degm/bondm (L3-warm; no mask round-trip),
// write mask_ln, 32 exps -> bf16 A-frags packed in registers, 16 MFMAs.
// No LDS, no __syncthreads, 2-deep manual prefetch of the HBM streams
// (named variables only -- R2's scratch-spill lesson).
// grid (kN/64, nq) x 256thr; acc[4][4] f32x4 = 64 VGPR.
// ---------------------------------------------------------------------------
__global__ __launch_bounds__(256) void k_aggr(
    const float* __restrict__ degm, const float* __restrict__ bondm,
    const float* __restrict__ ga, const float* __restrict__ gb,
    const int* __restrict__ cutp,
    const unsigned short* __restrict__ pSpack,
    const float* __restrict__ statg2,
    float* __restrict__ accpart, float* __restrict__ mlnp, int span)
{
  const int tid  = threadIdx.x;
  const int w    = tid >> 6;
  const int L    = tid & 63;
  const int rbase= blockIdx.x*64 + w*16;
  const int row  = rbase + (L & 15);
  const int colg = (L >> 4) * 8;
  const int jq   = blockIdx.y;
  const int jq0  = jq * span;
  const int nchunk = span >> 5;
  const float cut = (float)cutp[0];

  const float mu = statg2[2*row+0];
  const float rs = statg2[2*row+1];
  float av[kH];
  #pragma unroll
  for (int h = 0; h < kH; ++h) av[h] = ga[h*kN + row];

  f32x4 acc[kH][4];
  #pragma unroll
  for (int h = 0; h < kH; ++h)
    #pragma unroll
    for (int nt = 0; nt < 4; ++nt) acc[h][nt] = (f32x4){0.f,0.f,0.f,0.f};

  const size_t rowbase = (size_t)row * kN;

  // prefetch chunk 0
  float4 dg0 = *(const float4*)&degm[rowbase + jq0 + colg];
  float4 dg1 = *(const float4*)&degm[rowbase + jq0 + colg + 4];
  float4 bd0 = *(const float4*)&bondm[rowbase + jq0 + colg];
  float4 bd1 = *(const float4*)&bondm[rowbase + jq0 + colg + 4];

  for (int c = 0; c < nchunk; ++c){
    const int cb = jq0 + (c << 5);
    // issue next chunk's HBM loads before computing this one
    float4 ndg0 = dg0, ndg1 = dg1, nbd0 = bd0, nbd1 = bd1;
    if (c+1 < nchunk){
      const size_t noff = rowbase + cb + 32 + colg;
      ndg0 = *(const float4*)&degm[noff];
      ndg1 = *(const float4*)&degm[noff + 4];
      nbd0 = *(const float4*)&bondm[noff];
      nbd1 = *(const float4*)&bondm[noff + 4];
    }

    const float dgv[8] = {dg0.x,dg0.y,dg0.z,dg0.w, dg1.x,dg1.y,dg1.z,dg1.w};
    const float bdv[8] = {bd0.x,bd0.y,bd0.z,bd0.w, bd1.x,bd1.y,bd1.z,bd1.w};
    float m[8], ml[8];
    #pragma unroll
    for (int r = 0; r < 8; ++r){
      const float wv = dgv[r] + bdv[r];
      m[r]  = wv > 0.f ? wv : (bdv[r] > cut ? bdv[r] + wv : kNegInf);
      ml[r] = m[r] * kL2E;
    }
    // mask_ln output
    {
      float4 o0, o1;
      o0.x = (m[0]-mu)*rs; o0.y = (m[1]-mu)*rs;
      o0.z = (m[2]-mu)*rs; o0.w = (m[3]-mu)*rs;
      o1.x = (m[4]-mu)*rs; o1.y = (m[5]-mu)*rs;
      o1.z = (m[6]-mu)*rs; o1.w = (m[7]-mu)*rs;
      *(float4*)&mlnp[rowbase + cb + colg]     = o0;
      *(float4*)&mlnp[rowbase + cb + colg + 4] = o1;
    }
    const int kb = cb >> 5;
    #pragma unroll
    for (int h = 0; h < kH; ++h){
      const float4 g0 = *(const float4*)&gb[h*kN + cb + colg];
      const float4 g1 = *(const float4*)&gb[h*kN + cb + colg + 4];
      const float gv[8] = {g0.x,g0.y,g0.z,g0.w, g1.x,g1.y,g1.z,g1.w};
      union { unsigned u[4]; bf16x8 v; } ua;
      #pragma unroll
      for (int r2 = 0; r2 < 4; ++r2){
        float t0 = av[h] + gv[2*r2],   t1 = av[h] + gv[2*r2+1];
        t0 = fmaxf(t0, 0.2f*t0);       t1 = fmaxf(t1, 0.2f*t1);
        const float e0 = exp2f(fmaf(t0, kL2E, ml[2*r2]));
        const float e1 = exp2f(fmaf(t1, kL2E, ml[2*r2+1]));
        ua.u[r2] = f2bf_pk(e0, e1);
      }
      #pragma unroll
      for (int nt = 0; nt < 4; ++nt){
        const bf16x8 b = *(const bf16x8*)&pSpack[(size_t)(((h*128 + kb)*4 + nt)*64 + L)*8];
        acc[h][nt] = __builtin_amdgcn_mfma_f32_16x16x32_bf16(ua.v, b, acc[h][nt], 0, 0, 0);
      }
    }
    dg0 = ndg0; dg1 = ndg1; bd0 = nbd0; bd1 = nbd1;
  }

  // epilogue: C/D layout col=lane&15, row=(lane>>4)*4+reg
  #pragma unroll
  for (int h = 0; h < kH; ++h)
    #pragma unroll
    for (int nt = 0; nt < 4; ++nt)
      #pragma unroll
      for (int reg = 0; reg < 4; ++reg){
        const int i = rbase + (L >> 4)*4 + reg;
        const int f = h*64 + nt*16 + (L & 15);
        accpart[((size_t)jq*kN + i)*kHF + f] = acc[h][nt][reg];
      }
}

// ---------------------------------------------------------------------------
// K4: out = elu(sum_q accpart[q] + skip)
// ---------------------------------------------------------------------------
__global__ __launch_bounds__(256) void k_out(
    const float* __restrict__ accpart, const float* __restrict__ skipo,
    float* __restrict__ outp, int nq)
{
  const int idx = blockIdx.x * 256 + threadIdx.x;
  float o = skipo[idx];
  for (int q = 0; q < nq; ++q) o += accpart[(size_t)q*kN*kHF + idx];
  o = o > 0.f ? o : expm1f(o);
  outp[idx] = o;
}

// ---------------------------------------------------------------------------
extern "C" void kernel_launch(void* const* d_in, const int* in_sizes, int n_in,
                              void* d_out, int out_size, void* d_ws, size_t ws_size,
                              hipStream_t stream)
{
  const float* nodes = (const float*)d_in[0];
  const float* degm  = (const float*)d_in[1];
  const float* bondm = (const float*)d_in[3];
  const float* pp    = (const float*)d_in[4];
  const float* ssrc  = (const float*)d_in[5];
  const float* stgt  = (const float*)d_in[6];
  const float* skw   = (const float*)d_in[7];
  const int*   cutp  = (const int*)d_in[8];

  // ---- geometry: nq j-slices for k_aggr; Spart aliases accpart region ----
  const size_t fixed_floats = (size_t)kH*kN*kFO + 3*(size_t)kH*kN
                            + (size_t)kN*kHF + 4*(size_t)kN + (size_t)kFI*kHF;
  const size_t psp_floats = ((size_t)kH*kN*kFO)/2;
  const size_t need16 = (fixed_floats + (size_t)16*kN*kHF + psp_floats)*sizeof(float);
  const size_t need8  = (fixed_floats + (size_t)8*kN*kHF  + psp_floats)*sizeof(float);

  int nq, strips;
  if      (ws_size >= need16){ nq = 16; strips = 512; }
  else if (ws_size >= need8) { nq = 8;  strips = 512; }
  else                       { nq = 4;  strips = 256; }

  float* ws     = (float*)d_ws;
  float* proj   = ws;                               // 1,048,576
  float* ga     = proj + (size_t)kH*kN*kFO;         // 16384
  float* gb     = ga + kH*kN;                       // 16384
  float* statg  = gb + kH*kN;                       // 8192
  float* statg2 = statg + 2*kN;                     // 8192
  float* S      = statg2 + 2*kN;                    // 16384 (zeroed: k_sred atomics)
  float* skip   = S + kH*kN;                        // 1,048,576
  float* skwT   = skip + (size_t)kN*kHF;            // 32768
  float* accpart= skwT + (size_t)kFI*kHF;           // nq x N x HF
  float* Spart  = accpart;                          // alias: dead before k_aggr
  unsigned short* pSpack = (unsigned short*)(accpart + (size_t)nq*kN*kHF);

  float* outp = (float*)d_out;
  float* mlnp = outp + (size_t)kN*kHF;

  // zero statg + statg2 (harmless) + S (atomic targets)
  hipMemsetAsync(statg, 0, (4*(size_t)kN + (size_t)kH*kN)*sizeof(float), stream);

  k_tr<<<kFI, 256, 0, stream>>>(skw, skwT);
  k_proj<<<kN/8, 256, 0, stream>>>(nodes, pp, ssrc, stgt, skwT, proj, ga, gb, skip);
  if (strips == 512)
    k_colsum<8><<<dim3(kN/1024, 512), 256, 0, stream>>>(degm, bondm, ga, gb, cutp,
                                                        Spart, statg);
  else
    k_colsum<16><<<dim3(kN/1024, 256), 256, 0, stream>>>(degm, bondm, ga, gb, cutp,
                                                         Spart, statg);
  k_sred<<<dim3((kH*kN)/64, 8), 256, 0, stream>>>(Spart, S, strips);
  k_stat<<<kN/256, 256, 0, stream>>>(statg, statg2);
  k_pack<<<(kH*128*4*64)/256, 256, 0, stream>>>(proj, S, pSpack);
  k_aggr<<<dim3(kN/64, nq), 256, 0, stream>>>(degm, bondm, ga, gb, cutp,
                                              pSpack, statg2, accpart, mlnp,
                                              kN/nq);
  k_out<<<(kN*kHF)/256, 256, 0, stream>>>(accpart, skip, outp, nq);
}